// Round 6
// baseline (432.214 us; speedup 1.0000x reference)
//
#include <hip/hip_runtime.h>

// CRF log-likelihood, round 13: r12 skeleton (4-wave scan blocks, s_barrier,
// self-frag identity) + chain shortening:
//  - 8 fully INDEPENDENT MFMAs (one acc per slot per m-tile, no depth-2
//    chaining); 2-level f32x4 merge tree. Last-arriving operand (bo2) feeds
//    a leaf, so post-arrival tail = 1 MFMA + 2 adds (was 1 MFMA chained + add).
//  - renorm folded off-chain: cex = cis*ex computed during the MFMA block;
//    output ov = cex*s (+ injf*ex on bwd inject steps). One dependent VALU
//    level instead of two. bwd capture recomputes rv = cis*s in its rare branch.
//  - sprev (scale) LDS read issued first after barrier.
//
// Identity (r8/r10-verified): mfma_f32_16x16x32_bf16 C/D row = 4*(lane>>4)+reg,
// col = lane&15; B-frag k = 32c + 16*(jj>>2) + 4*(lane>>4) + (jj&3). Wave W
// owns rows 32W..32W+31 == k-chunk c=W of the next state: pack2(ov) is
// bit-for-bit its own slot-0 B operand.
//
// crf_scan grid = 96 blocks x 256 thr:
//   blocks 0..15  : FORWARD scan, t = 1..cmax, capture q_cb.
//   blocks 16..31 : BACKWARD scan r_{t-1} = E(u_t.*r_t), capture r_cb;
//                   cb==tfin batches capture ones at init.
//   blocks 32..95 : unary+binary scores (4 batches each), concurrent.
// crf_comb: logZ = ln2*(log2(dot(qcap,rcap)) + Dq + Dr); out = score - logZ.

#define B_   256
#define LL   1024
#define TT   128
#define NBLK 16
#define L2E  1.4426950408889634f
#define LN2f 0.6931471805599453f

typedef __attribute__((ext_vector_type(8))) short bf16x8;
typedef __attribute__((ext_vector_type(4))) float f32x4;
union bfrw { unsigned w[4]; bf16x8 v; };

__device__ __forceinline__ unsigned bfround(float x) {   // RNE bf16 bits in [31:16]
    unsigned u = __float_as_uint(x);
    return u + 0x7fffu + ((u >> 16) & 1u);
}
__device__ __forceinline__ unsigned pack2(float lo, float hi) {  // [hi|lo] bf16 pair
#if __has_builtin(__builtin_amdgcn_cvt_pk_bf16_f32)
    auto p = __builtin_amdgcn_cvt_pk_bf16_f32(lo, hi);
    unsigned w; __builtin_memcpy(&w, &p, 4); return w;
#else
    return __builtin_amdgcn_perm(bfround(hi), bfround(lo), 0x07060302);
#endif
}
__device__ __forceinline__ void lds_barrier() {
    asm volatile("s_waitcnt lgkmcnt(0)\n\ts_barrier" ::: "memory");
}

// fragls: [buf 0/1][cg 0..3][lane 0..63] x 16B. Wave W writes cg=W (its
// packed next-state frag), keeps a register copy (bs), reads the other 3.
// af[m][i]: slot i -> cg {W, c1, c2, c3} (others ascending).

template<bool FWD, int PH>
__device__ __forceinline__ void phase(int t, float& Dacc,
                                      float4 (&up)[4][2],
                                      const bf16x8 (&af)[2][4],
                                      bf16x8& bs,
                                      short* fragls, float* sbuf,
                                      const float* pu,
                                      float* capl, float* dcap,
                                      int o0, int o1, int o2, int ws,
                                      int cb, int tfin, int W, int q, int b)
{
    constexpr int CUR  = PH & 1;
    constexpr int NXT  = CUR ^ 1;
    constexpr int SLOT = FWD ? ((1 + PH) & 3) : ((3 - PH) & 3);

    // scale first (earliest consumer chain), then partner frags
    float sprev = sbuf[CUR * 16 + b];
    bf16x8 bo0 = *(const bf16x8*)(fragls + CUR * 2048 + o0);
    bf16x8 bo1 = *(const bf16x8*)(fragls + CUR * 2048 + o1);
    bf16x8 bo2 = *(const bf16x8*)(fragls + CUR * 2048 + o2);

    // ---- 8 fully independent MFMAs: per m-tile one acc per slot ----
    const f32x4 z = {0.f, 0.f, 0.f, 0.f};
    f32x4 a00 = __builtin_amdgcn_mfma_f32_16x16x32_bf16(af[0][0], bs,  z, 0, 0, 0);
    f32x4 a10 = __builtin_amdgcn_mfma_f32_16x16x32_bf16(af[1][0], bs,  z, 0, 0, 0);
    f32x4 a01 = __builtin_amdgcn_mfma_f32_16x16x32_bf16(af[0][1], bo0, z, 0, 0, 0);
    f32x4 a11 = __builtin_amdgcn_mfma_f32_16x16x32_bf16(af[1][1], bo0, z, 0, 0, 0);
    f32x4 a02 = __builtin_amdgcn_mfma_f32_16x16x32_bf16(af[0][2], bo1, z, 0, 0, 0);
    f32x4 a12 = __builtin_amdgcn_mfma_f32_16x16x32_bf16(af[1][2], bo1, z, 0, 0, 0);
    f32x4 a03 = __builtin_amdgcn_mfma_f32_16x16x32_bf16(af[0][3], bo2, z, 0, 0, 0);
    f32x4 a13 = __builtin_amdgcn_mfma_f32_16x16x32_bf16(af[1][3], bo2, z, 0, 0, 0);

    // renorm scalars + u exp + cex folding — all under MFMA latency
    float ci = __builtin_amdgcn_rcpf(sprev);
    float lg = __builtin_amdgcn_logf(sprev);          // v_log_f32 = log2
    bool inj = (!FWD) && (tfin == t - 1);
    float cis  = inj ? 0.f : ci;
    float injf = inj ? 1.f : 0.f;
    Dacc = inj ? 0.f : (Dacc + lg);

    float ex[2][4], cex[2][4];
    #pragma unroll
    for (int m = 0; m < 2; ++m) {
        float4 v = up[SLOT][m];
        ex[m][0] = __builtin_amdgcn_exp2f(v.x * L2E);
        ex[m][1] = __builtin_amdgcn_exp2f(v.y * L2E);
        ex[m][2] = __builtin_amdgcn_exp2f(v.z * L2E);
        ex[m][3] = __builtin_amdgcn_exp2f(v.w * L2E);
        #pragma unroll
        for (int r = 0; r < 4; ++r) cex[m][r] = cis * ex[m][r];
    }
    {   // prefetch into the freed slot (consumed 4 steps later)
        int tp = FWD ? (t + 4) : (t - 5);
        tp = tp < 0 ? 0 : (tp > LL - 1 ? LL - 1 : tp);
        const float* pt = pu + (size_t)tp * TT;
        up[SLOT][0] = *(const float4*)(pt);
        up[SLOT][1] = *(const float4*)(pt + 16);
    }

    // ---- 2-level merge tree (chain after bo2 arrival: 1 MFMA + 2 adds) ----
    f32x4 s0 = (a00 + a01) + (a02 + a03);
    f32x4 s1 = (a10 + a11) + (a12 + a13);

    if (!FWD) {
        bool cap = (cb == t - 1) && (cb != tfin);     // cap => !inj
        if (__any(cap)) {
            if (cap) {                                 // rare: recompute rv
                float4 c0 = {cis*s0[0], cis*s0[1], cis*s0[2], cis*s0[3]};
                float4 c1 = {cis*s1[0], cis*s1[1], cis*s1[2], cis*s1[3]};
                *(float4*)(capl + b * TT + 32 * W + q * 4)      = c0;
                *(float4*)(capl + b * TT + 32 * W + 16 + q * 4) = c1;
                if (W == 0 && q == 0) dcap[b] = Dacc;
            }
        }
    }

    // output: one dependent level. fwd: ov = cex*s. bwd: ov = cex*s + injf*ex.
    float ov[2][4];
    if (FWD) {
        #pragma unroll
        for (int r = 0; r < 4; ++r) {
            ov[0][r] = cex[0][r] * s0[r];
            ov[1][r] = cex[1][r] * s1[r];
        }
    } else {
        #pragma unroll
        for (int r = 0; r < 4; ++r) {
            ov[0][r] = cex[0][r] * s0[r] + injf * ex[0][r];
            ov[1][r] = cex[1][r] * s1[r] + injf * ex[1][r];
        }
    }

    if (FWD) {
        bool cap = (cb == t);
        if (__any(cap)) {
            if (cap) {
                float4 c0 = {ov[0][0], ov[0][1], ov[0][2], ov[0][3]};
                float4 c1 = {ov[1][0], ov[1][1], ov[1][2], ov[1][3]};
                *(float4*)(capl + b * TT + 32 * W + q * 4)      = c0;
                *(float4*)(capl + b * TT + 32 * W + 16 + q * 4) = c1;
                if (W == 0 && q == 0) dcap[b] = Dacc;
            }
        }
    }

    // raw S0 for next step's renorm: global row 0 = wave 0, m=0, q=0, reg 0
    if (W == 0 && q == 0) sbuf[NXT * 16 + b] = s0[0];

    // pack self next-state frag (identity: frag W <- m-tiles {2W, 2W+1})
    bfrw pk;
    pk.w[0] = pack2(ov[0][0], ov[0][1]);
    pk.w[1] = pack2(ov[0][2], ov[0][3]);
    pk.w[2] = pack2(ov[1][0], ov[1][1]);
    pk.w[3] = pack2(ov[1][2], ov[1][3]);
    bs = pk.v;
    *(bf16x8*)(fragls + NXT * 2048 + ws) = pk.v;

    lds_barrier();
}

__launch_bounds__(256, 1)
__global__ void crf_scan(const float* __restrict__ inputs,
                         const int*   __restrict__ tags,
                         const int*   __restrict__ slens,
                         const float* __restrict__ trans,
                         float* __restrict__ qcap, float* __restrict__ rcap,
                         float* __restrict__ dqv,  float* __restrict__ drv,
                         int* __restrict__ perm, float* __restrict__ scorebuf)
{
    __shared__ __align__(16) short fragls[2 * 4 * 64 * 8];   // 8 KB exchange
    __shared__ __align__(16) float capl[16 * TT];            // 8 KB captures
    __shared__ float dcap[16];
    __shared__ float sbuf[2 * 16];
    __shared__ float ssb[4];
    __shared__ int keys[B_];

    const int tid = threadIdx.x;

    // ---------------- score blocks (32..95): 4 batches each ----------------
    if (blockIdx.x >= 2 * NBLK) {
        const int sbid = blockIdx.x - 2 * NBLK;     // 0..63
        const int lane = tid & 63, w = tid >> 6;
        #pragma unroll 1
        for (int bi = 0; bi < 4; ++bi) {
            const int b = sbid * 4 + bi;
            const int slen = slens[b];
            const float* inb  = inputs + (size_t)b * LL * TT;
            const int*   tagb = tags + b * LL;
            float sc = 0.f;
            for (int t = tid; t < slen; t += 256) {
                int tg = tagb[t];
                float v = inb[(size_t)t * TT + tg];
                if (t >= 1) v += trans[tagb[t - 1] * TT + tg];
                sc += v;
            }
            #pragma unroll
            for (int off = 32; off > 0; off >>= 1) sc += __shfl_xor(sc, off, 64);
            if (lane == 0) ssb[w] = sc;
            __syncthreads();
            if (tid == 0) scorebuf[b] = ssb[0] + ssb[1] + ssb[2] + ssb[3];
            __syncthreads();
        }
        return;
    }

    // ---------------- scan blocks (0..31) ----------------
    // deterministic bitonic sort of (slen, batch) keys — identical all blocks
    keys[tid] = slens[tid] * 256 + tid;
    __syncthreads();
    for (int k = 2; k <= B_; k <<= 1) {
        for (int s = k >> 1; s > 0; s >>= 1) {
            int ixj = tid ^ s;
            if (ixj > tid) {
                int a = keys[tid], b2 = keys[ixj];
                bool asc = ((tid & k) == 0);
                if ((a > b2) == asc) { keys[tid] = b2; keys[ixj] = a; }
            }
            __syncthreads();
        }
    }

    const bool isf = (blockIdx.x < NBLK);
    const int g    = isf ? blockIdx.x : blockIdx.x - NBLK;
    if (isf && tid < 16) perm[g * 16 + tid] = keys[g * 16 + tid] & 255;

    const int lane = tid & 63;
    const int W    = __builtin_amdgcn_readfirstlane(tid >> 6);   // 0..3
    const int q    = lane >> 4;
    const int b    = lane & 15;

    const int key = keys[g * 16 + b];
    const int ob  = key & 255;
    const int sl  = key >> 8;
    int tfin = sl - 1; if (tfin < 1) tfin = 1;

    int tmax = tfin;
    #pragma unroll
    for (int o = 1; o < 16; o <<= 1) {
        int c2 = __shfl_xor(tmax, o, 16); tmax = c2 > tmax ? c2 : tmax;
    }
    tmax = __builtin_amdgcn_readfirstlane(tmax);

    const int C  = (tmax + 4) >> 1;             // balanced cut (>=2)
    const int cb = tfin < C ? tfin : C;

    int cmax = cb, cmin = cb;
    #pragma unroll
    for (int o = 1; o < 16; o <<= 1) {
        int a = __shfl_xor(cmax, o, 16); cmax = a > cmax ? a : cmax;
        int b2 = __shfl_xor(cmin, o, 16); cmin = b2 < cmin ? b2 : cmin;
    }
    cmax = __builtin_amdgcn_readfirstlane(cmax);
    cmin = __builtin_amdgcn_readfirstlane(cmin);

    const int tb0 = (tmax + 4) & ~3;            // bwd start, == 0 mod 4

    // slot -> cg mapping: {W, others ascending}
    const int c1 = (W == 0) ? 1 : 0;
    const int c2 = (W <= 1) ? 2 : 1;
    const int c3 = (W <= 2) ? 3 : 2;
    const int o0 = (c1 * 64 + lane) * 8;
    const int o1 = (c2 * 64 + lane) * 8;
    const int o2 = (c3 * 64 + lane) * 8;
    const int ws = (W  * 64 + lane) * 8;

    // E fragments: af[m][i], slot i -> cg {W,c1,c2,c3};
    // j = 32W + 16m + b; k = 32c + 16*(jj>>2) + 4q + (jj&3) (verified)
    bf16x8 af[2][4];
    #pragma unroll
    for (int m = 0; m < 2; ++m) {
        const int j = 32 * W + 16 * m + b;
        #pragma unroll
        for (int i = 0; i < 4; ++i) {
            const int c = (i == 0) ? W : (i == 1) ? c1 : (i == 2) ? c2 : c3;
            #pragma unroll
            for (int jj = 0; jj < 8; ++jj) {
                int k = 32 * c + 16 * (jj >> 2) + 4 * q + (jj & 3);
                int idx = isf ? (k * TT + j) : (j * TT + k);
                float ev = __builtin_amdgcn_exp2f(trans[idx] * L2E);
                af[m][i][jj] = (short)(bfround(ev) >> 16);
            }
        }
    }

    const float* pu = inputs + (size_t)ob * LL * TT + 32 * W + q * 4;
    float Dacc = 0.f;
    float4 up[4][2];
    bf16x8 bs;

    if (tid < 16) sbuf[tid] = 1.0f;             // initial scale (buf 0)

    if (isf) {
        // init q0 = exp(in[0][j]) -> self frag + LDS buf0 (cb>=1: no init cap)
        float q0[2][4];
        #pragma unroll
        for (int m = 0; m < 2; ++m) {
            float4 v = *(const float4*)(pu + m * 16);
            q0[m][0] = __builtin_amdgcn_exp2f(v.x * L2E);
            q0[m][1] = __builtin_amdgcn_exp2f(v.y * L2E);
            q0[m][2] = __builtin_amdgcn_exp2f(v.z * L2E);
            q0[m][3] = __builtin_amdgcn_exp2f(v.w * L2E);
        }
        bfrw pk;
        pk.w[0] = pack2(q0[0][0], q0[0][1]);
        pk.w[1] = pack2(q0[0][2], q0[0][3]);
        pk.w[2] = pack2(q0[1][0], q0[1][1]);
        pk.w[3] = pack2(q0[1][2], q0[1][3]);
        bs = pk.v;
        *(bf16x8*)(fragls + ws) = pk.v;

        #pragma unroll
        for (int s = 1; s <= 4; ++s) {
            up[s & 3][0] = *(const float4*)(pu + (size_t)s * TT);
            up[s & 3][1] = *(const float4*)(pu + (size_t)s * TT + 16);
        }
        __syncthreads();

        for (int tb = 1; tb <= cmax; tb += 4) {
            phase<true,0>(tb+0, Dacc, up, af, bs, fragls, sbuf, pu, capl, dcap, o0,o1,o2,ws, cb, tfin, W, q, b);
            phase<true,1>(tb+1, Dacc, up, af, bs, fragls, sbuf, pu, capl, dcap, o0,o1,o2,ws, cb, tfin, W, q, b);
            phase<true,2>(tb+2, Dacc, up, af, bs, fragls, sbuf, pu, capl, dcap, o0,o1,o2,ws, cb, tfin, W, q, b);
            phase<true,3>(tb+3, Dacc, up, af, bs, fragls, sbuf, pu, capl, dcap, o0,o1,o2,ws, cb, tfin, W, q, b);
        }
    } else {
        // init w = 1.0; batches with cb == tfin capture ones / Dr = 0 here
        bfrw pk;
        pk.w[0] = pk.w[1] = pk.w[2] = pk.w[3] = 0x3F803F80u;
        bs = pk.v;
        *(bf16x8*)(fragls + ws) = pk.v;
        if (cb == tfin) {
            float4 one4 = {1.f, 1.f, 1.f, 1.f};
            *(float4*)(capl + b * TT + 32 * W + q * 4)      = one4;
            *(float4*)(capl + b * TT + 32 * W + 16 + q * 4) = one4;
            if (W == 0 && q == 0) dcap[b] = 0.f;
        }
        #pragma unroll
        for (int ph = 0; ph < 4; ++ph) {
            int ui = tb0 - 1 - ph;
            ui = ui > LL - 1 ? LL - 1 : (ui < 0 ? 0 : ui);
            up[(3 - ph) & 3][0] = *(const float4*)(pu + (size_t)ui * TT);
            up[(3 - ph) & 3][1] = *(const float4*)(pu + (size_t)ui * TT + 16);
        }
        __syncthreads();

        for (int tb = tb0; tb > cmin; tb -= 4) {
            phase<false,0>(tb-0, Dacc, up, af, bs, fragls, sbuf, pu, capl, dcap, o0,o1,o2,ws, cb, tfin, W, q, b);
            phase<false,1>(tb-1, Dacc, up, af, bs, fragls, sbuf, pu, capl, dcap, o0,o1,o2,ws, cb, tfin, W, q, b);
            phase<false,2>(tb-2, Dacc, up, af, bs, fragls, sbuf, pu, capl, dcap, o0,o1,o2,ws, cb, tfin, W, q, b);
            phase<false,3>(tb-3, Dacc, up, af, bs, fragls, sbuf, pu, capl, dcap, o0,o1,o2,ws, cb, tfin, W, q, b);
        }
    }

    // copy captures out (last lds_barrier synced + drained everything)
    float* gout = isf ? qcap : rcap;
    #pragma unroll
    for (int i = 0; i < 2; ++i) {
        float4 v = *(const float4*)(capl + i * 1024 + tid * 4);
        *(float4*)(gout + (size_t)g * 16 * TT + i * 1024 + tid * 4) = v;
    }
    if (tid < 16) (isf ? dqv : drv)[g * 16 + tid] = dcap[tid];
}

__global__ void crf_comb(const float* __restrict__ qcap, const float* __restrict__ rcap,
                         const float* __restrict__ dqv, const float* __restrict__ drv,
                         const int* __restrict__ perm, const float* __restrict__ scorebuf,
                         float* __restrict__ out) {
    const int tid = threadIdx.x;
    const int r16 = tid >> 4, part = tid & 15;
    const int rank = blockIdx.x * 16 + r16;
    const float* qc = qcap + rank * TT + part * 8;
    const float* rc = rcap + rank * TT + part * 8;
    float4 a0 = *(const float4*)(qc);
    float4 a1 = *(const float4*)(qc + 4);
    float4 b0 = *(const float4*)(rc);
    float4 b1 = *(const float4*)(rc + 4);
    float s = a0.x*b0.x + a0.y*b0.y + a0.z*b0.z + a0.w*b0.w
            + a1.x*b1.x + a1.y*b1.y + a1.z*b1.z + a1.w*b1.w;
    #pragma unroll
    for (int o = 1; o < 16; o <<= 1) s += __shfl_xor(s, o, 16);
    if (part == 0) {
        int ob = perm[rank];
        float logZ = LN2f * (__builtin_amdgcn_logf(s) + dqv[rank] + drv[rank]);
        out[ob] = scorebuf[ob] - logZ;
    }
}

extern "C" void kernel_launch(void* const* d_in, const int* in_sizes, int n_in,
                              void* d_out, int out_size, void* d_ws, size_t ws_size,
                              hipStream_t stream) {
    const float* inputs = (const float*)d_in[0];
    const int*   tags   = (const int*)d_in[1];
    const int*   slens  = (const int*)d_in[2];
    const float* trans  = (const float*)d_in[3];
    float* out = (float*)d_out;

    float* qcap = (float*)d_ws;            // 256*128 f32
    float* rcap = qcap + 32768;            // 256*128 f32
    float* dqv  = rcap + 32768;            // 256
    float* drv  = dqv + 256;               // 256
    int*   perm = (int*)(drv + 256);       // 256
    float* scorebuf = (float*)(perm + 256);// 256

    crf_scan<<<2 * NBLK + 64, 256, 0, stream>>>(inputs, tags, slens, trans,
                                                qcap, rcap, dqv, drv, perm, scorebuf);
    crf_comb<<<NBLK, 256, 0, stream>>>(qcap, rcap, dqv, drv, perm, scorebuf, out);
}